// Round 6
// baseline (1569.471 us; speedup 1.0000x reference)
//
#include <hip/hip_runtime.h>
#include <hip/hip_bf16.h>

#define B_   4
#define CIN  64
#define HID  256
#define COUT 64
#define T_   16
#define H_   64
#define W_   64
#define HW_  (H_*W_)       // 4096
#define THW  (T_*HW_)      // 65536
#define EPS  1e-5f

typedef unsigned short ushort_t;
typedef unsigned int   uint_t;
typedef short bf16x8 __attribute__((ext_vector_type(8)));
typedef float f32x4  __attribute__((ext_vector_type(4)));

// ---- stats + accumulators in static device memory ----------------------------
#define SM1   0
#define SIS1  1024
#define SM2   2048
#define SIS2  3072
#define SM3   4096
#define SIS3  5120
#define SSES  6144
#define SAL   7168
#define SBE   8192
#define SMP   9216
#define SISP  9472
// atomic accumulators (zeroed by k_zero each iteration)
#define SUM1  10240
#define SSQ1  11264
#define SUM2  12288
#define SSQ2  13312
#define SUM3  14336
#define SSQ3  15360
#define SUMP  16384
#define SSQP  17408
__device__ float g_stats[18432];
// packed bf16 weights in MFMA fragment order: [0:16384) expand, [16384:32768) proj
__device__ ushort_t g_wpack[32768];

__device__ __forceinline__ float bf2f(ushort_t u) {
    return __uint_as_float(((uint_t)u) << 16);
}
__device__ __forceinline__ ushort_t f2bf(float f) {
    uint_t u = __float_as_uint(f);
    uint_t r = u + 0x7fffu + ((u >> 16) & 1u);   // round-to-nearest-even
    return (ushort_t)(r >> 16);
}
__device__ __forceinline__ void loadnorm8(const ushort_t* p, float a, float bb,
                                          float* v) {
    uint4 u = *(const uint4*)p;
    uint_t uu[4] = {u.x, u.y, u.z, u.w};
    #pragma unroll
    for (int j = 0; j < 4; ++j) {
        v[2*j]   = fmaxf(fmaf(__uint_as_float(uu[j] << 16),         a, bb), 0.f);
        v[2*j+1] = fmaxf(fmaf(__uint_as_float(uu[j] & 0xffff0000u), a, bb), 0.f);
    }
}
// block-wide {s,ss} reduce + 2 atomics (per-channel-uniform blocks)
__device__ __forceinline__ void block_stats_atomic(float s, float ss, int sumi, int ssqi) {
    #pragma unroll
    for (int m = 32; m > 0; m >>= 1) {
        s  += __shfl_xor(s,  m);
        ss += __shfl_xor(ss, m);
    }
    __shared__ float ls[4], lss[4];
    int wid = threadIdx.x >> 6, lane = threadIdx.x & 63;
    if (lane == 0) { ls[wid] = s; lss[wid] = ss; }
    __syncthreads();
    if (threadIdx.x == 0) {
        atomicAdd(&g_stats[sumi], ls[0]+ls[1]+ls[2]+ls[3]);
        atomicAdd(&g_stats[ssqi], lss[0]+lss[1]+lss[2]+lss[3]);
    }
}

// ---- zero the atomic accumulators --------------------------------------------
__global__ __launch_bounds__(256) void k_zero() {
    #pragma unroll
    for (int i = 0; i < 32; ++i)
        g_stats[SUM1 + i*256 + threadIdx.x] = 0.f;
}

// ---- pack w1 + wproj into bf16 fragment order --------------------------------
// expand: pack[((wv*2+ks)*4+ot)*512 + lane*8 + j] = w1[o=wv*64+ot*16+ln][k=ks*32+q*8+j]
// proj:   pack[16384 + (kg*4+ot)*512 + lane*8 + j] = wproj[o=ot*16+ln][k=kg*32+q*8+j]
__global__ __launch_bounds__(256) void k_prep(const float* __restrict__ w1,
                                              const float* __restrict__ wproj) {
    int idx = blockIdx.x*256 + threadIdx.x;        // 0..16383
    {
        int j = idx & 7, lane = (idx>>3) & 63, ot = (idx>>9) & 3;
        int ks = (idx>>11) & 1, wv = idx >> 12;
        int ln = lane & 15, q = lane >> 4;
        int o = wv*64 + ot*16 + ln, k = ks*32 + q*8 + j;
        g_wpack[idx] = f2bf(w1[o*CIN + k]);
    }
    {
        int j = idx & 7, lane = (idx>>3) & 63, ot = (idx>>9) & 3, kg = idx >> 11;
        int ln = lane & 15, q = lane >> 4;
        int o = ot*16 + ln, k = kg*32 + q*8 + j;
        g_wpack[16384 + idx] = f2bf(wproj[o*HID + k]);
    }
}

// ---- finalize: mean / inv_sd from sums ---------------------------------------
__global__ __launch_bounds__(256) void k_fin(int sumoff, int ssqoff,
                                             int moff, int isoff, int nch) {
    for (int i = threadIdx.x; i < nch; i += 256) {
        float m = g_stats[sumoff + i] * (1.f/THW);
        float v = g_stats[ssqoff + i] * (1.f/THW) - m*m;
        g_stats[moff  + i] = m;
        g_stats[isoff + i] = 1.f / sqrtf(v + EPS);
    }
}

// ============ expand 1x1 via MFMA + fused stats ===============================
__global__ __launch_bounds__(256) void k_expand(const float* __restrict__ x,
                                                ushort_t* __restrict__ h1, int b0) {
    __shared__ ushort_t Bs[64*72];       // B[k][n], stride 72, rotated cols
    const int tid = threadIdx.x;
    const int bb  = blockIdx.y, gb = b0 + bb;
    const int pos0 = blockIdx.x * 64;
    const int lane = tid & 63, wv = tid >> 6;
    const int q = lane >> 4, ln = lane & 15;

    // A fragments straight from packed global (L2-hot, coalesced 16B/lane)
    bf16x8 af[2][4];
    #pragma unroll
    for (int ks = 0; ks < 2; ++ks)
        #pragma unroll
        for (int ot = 0; ot < 4; ++ot)
            af[ks][ot] = *(const bf16x8*)&g_wpack[(((wv*2+ks)*4+ot)<<9) + lane*8];

    // stage B: x [64 k x 64 n] fp32 -> bf16, rotated columns
    #pragma unroll
    for (int i = 0; i < 16; ++i) {
        int linear = i*256 + tid;
        int k = linear >> 6, n = linear & 63;
        float v = x[(size_t)(gb*CIN + k) * THW + pos0 + n];
        Bs[k*72 + ((n + 16*((k>>3)&3)) & 63)] = f2bf(v);
    }
    __syncthreads();

    f32x4 acc[4][4];
    #pragma unroll
    for (int i = 0; i < 4; ++i)
        #pragma unroll
        for (int j = 0; j < 4; ++j)
            acc[i][j] = (f32x4){0.f,0.f,0.f,0.f};

    #pragma unroll
    for (int ks = 0; ks < 2; ++ks) {
        bf16x8 bfr[4];
        #pragma unroll
        for (int nt = 0; nt < 4; ++nt) {
            union { short s[8]; bf16x8 v; } bu;
            #pragma unroll
            for (int j = 0; j < 8; ++j) {
                int k = ks*32 + q*8 + j;
                int nn = (nt*16 + ln + 16*((k>>3)&3)) & 63;
                bu.s[j] = (short)Bs[k*72 + nn];
            }
            bfr[nt] = bu.v;
        }
        #pragma unroll
        for (int ot = 0; ot < 4; ++ot)
            #pragma unroll
            for (int nt = 0; nt < 4; ++nt)
                acc[ot][nt] = __builtin_amdgcn_mfma_f32_16x16x32_bf16(
                    af[ks][ot], bfr[nt], acc[ot][nt], 0, 0, 0);
    }

    // epilogue + per-channel stats (C layout: col=ln -> n, row=q*4+r -> o)
    float sred[4][4], ssred[4][4];
    #pragma unroll
    for (int ot = 0; ot < 4; ++ot)
        #pragma unroll
        for (int r = 0; r < 4; ++r) { sred[ot][r] = 0.f; ssred[ot][r] = 0.f; }

    #pragma unroll
    for (int ot = 0; ot < 4; ++ot)
        #pragma unroll
        for (int nt = 0; nt < 4; ++nt)
            #pragma unroll
            for (int r = 0; r < 4; ++r) {
                int o = wv*64 + ot*16 + q*4 + r;
                int n = nt*16 + ln;
                ushort_t us = f2bf(acc[ot][nt][r]);
                h1[((size_t)bb*HID + o)*THW + pos0 + n] = us;
                float v = bf2f(us);
                sred[ot][r] += v;
                ssred[ot][r] = fmaf(v, v, ssred[ot][r]);
            }

    #pragma unroll
    for (int ot = 0; ot < 4; ++ot)
        #pragma unroll
        for (int r = 0; r < 4; ++r) {
            float s = sred[ot][r], ss = ssred[ot][r];
            #pragma unroll
            for (int m = 8; m > 0; m >>= 1) {     // reduce over ln within quad
                s  += __shfl_xor(s,  m);
                ss += __shfl_xor(ss, m);
            }
            if (ln == 0) {
                int c = bb*HID + wv*64 + ot*16 + q*4 + r;
                atomicAdd(&g_stats[SUM1 + c], s);
                atomicAdd(&g_stats[SSQ1 + c], ss);
            }
        }
}

// ============ proj 1x1 via MFMA (norm3+relu+SE folded) + fused stats ==========
__global__ __launch_bounds__(256) void k_proj(const ushort_t* __restrict__ h3,
                                              float* __restrict__ proj) {
    __shared__ ushort_t Bs[64*136];      // B[klocal][n], stride 136, rotated cols
    const int tid = threadIdx.x;
    const int bb  = blockIdx.y;
    const int pos0 = blockIdx.x * 128;
    const int lane = tid & 63, wv = tid >> 6;
    const int q = lane >> 4, ln = lane & 15;

    f32x4 acc[4][2];
    #pragma unroll
    for (int i = 0; i < 4; ++i) {
        acc[i][0] = (f32x4){0.f,0.f,0.f,0.f};
        acc[i][1] = (f32x4){0.f,0.f,0.f,0.f};
    }

    for (int kc = 0; kc < 4; ++kc) {
        #pragma unroll
        for (int i = 0; i < 32; ++i) {
            int linear = i*256 + tid;
            int kl = linear >> 7, n = linear & 127;
            int ch = bb*HID + kc*64 + kl;
            float raw = bf2f(h3[(size_t)ch * THW + pos0 + n]);
            float v = fmaxf(fmaf(raw, g_stats[SAL + ch], g_stats[SBE + ch]), 0.f);
            Bs[kl*136 + ((n + 16*((kl>>3)&7)) & 127)] = f2bf(v);
        }
        __syncthreads();

        #pragma unroll
        for (int ks = 0; ks < 2; ++ks) {
            int kg = kc*2 + ks;
            bf16x8 af[4];
            #pragma unroll
            for (int ot = 0; ot < 4; ++ot)
                af[ot] = *(const bf16x8*)&g_wpack[16384 + ((kg*4+ot)<<9) + lane*8];
            bf16x8 bfr[2];
            #pragma unroll
            for (int nt = 0; nt < 2; ++nt) {
                union { short s[8]; bf16x8 v; } bu;
                #pragma unroll
                for (int j = 0; j < 8; ++j) {
                    int kl = ks*32 + q*8 + j;
                    int nn = (wv*32 + nt*16 + ln + 16*((kl>>3)&7)) & 127;
                    bu.s[j] = (short)Bs[kl*136 + nn];
                }
                bfr[nt] = bu.v;
            }
            #pragma unroll
            for (int ot = 0; ot < 4; ++ot)
                #pragma unroll
                for (int nt = 0; nt < 2; ++nt)
                    acc[ot][nt] = __builtin_amdgcn_mfma_f32_16x16x32_bf16(
                        af[ot], bfr[nt], acc[ot][nt], 0, 0, 0);
        }
        __syncthreads();
    }

    float sred[4][4], ssred[4][4];
    #pragma unroll
    for (int ot = 0; ot < 4; ++ot)
        #pragma unroll
        for (int r = 0; r < 4; ++r) { sred[ot][r] = 0.f; ssred[ot][r] = 0.f; }

    #pragma unroll
    for (int ot = 0; ot < 4; ++ot)
        #pragma unroll
        for (int nt = 0; nt < 2; ++nt)
            #pragma unroll
            for (int r = 0; r < 4; ++r) {
                int o = ot*16 + q*4 + r;
                int n = wv*32 + nt*16 + ln;
                float v = acc[ot][nt][r];
                proj[((size_t)bb*COUT + o)*THW + pos0 + n] = v;
                sred[ot][r] += v;
                ssred[ot][r] = fmaf(v, v, ssred[ot][r]);
            }

    #pragma unroll
    for (int ot = 0; ot < 4; ++ot)
        #pragma unroll
        for (int r = 0; r < 4; ++r) {
            float s = sred[ot][r], ss = ssred[ot][r];
            #pragma unroll
            for (int m = 8; m > 0; m >>= 1) {
                s  += __shfl_xor(s,  m);
                ss += __shfl_xor(ss, m);
            }
            if (ln == 0) {
                int c = bb*COUT + ot*16 + q*4 + r;
                atomicAdd(&g_stats[SUMP + c], s);
                atomicAdd(&g_stats[SSQP + c], ss);
            }
        }
}

// ------------ spatial dw 3x3, 8-wide (+TIM, +norm1/relu, +fused stats) --------
__global__ __launch_bounds__(256) void k_dws(const ushort_t* __restrict__ h1,
                                             const float* __restrict__ wdw,
                                             ushort_t* __restrict__ h2) {
    const int tid = threadIdx.x;
    const int x0  = (tid & 7) * 8;
    const int y   = blockIdx.x * 32 + (tid >> 3);
    const int t   = blockIdx.y;
    const int bc  = blockIdx.z;
    const int o   = bc & (HID-1);
    const size_t outoff = (size_t)bc * THW + t*HW_ + y*W_ + x0;

    int ts = t; bool zero = false;
    if (o < 32)       { ts = t + 1; if (ts >= T_) zero = true; }
    else if (o < 64)  { zero = true; }
    if (zero) {                      // zeros contribute 0 to sums: skip atomics
        uint4 z = {0u,0u,0u,0u};
        *(uint4*)(h2 + outoff) = z;
        return;
    }

    const float a  = g_stats[SIS1 + bc];
    const float bb = -g_stats[SM1 + bc] * a;
    const ushort_t* sp = h1 + (size_t)bc * THW + ts*HW_;

    float wf[9];
    #pragma unroll
    for (int k = 0; k < 9; ++k) wf[k] = wdw[o*9 + k];

    float v[3][10];
    #pragma unroll
    for (int dy = 0; dy < 3; ++dy) {
        int yy = y + dy - 1;
        if (yy < 0 || yy >= H_) {
            #pragma unroll
            for (int j = 0; j < 10; ++j) v[dy][j] = 0.f;
        } else {
            const ushort_t* rp = sp + yy*W_;
            loadnorm8(rp + x0, a, bb, &v[dy][1]);
            v[dy][0] = (x0 == 0)  ? 0.f : fmaxf(fmaf(bf2f(rp[x0-1]), a, bb), 0.f);
            v[dy][9] = (x0 == 56) ? 0.f : fmaxf(fmaf(bf2f(rp[x0+8]), a, bb), 0.f);
        }
    }

    float s = 0.f, ss = 0.f;
    uint_t outp[4];
    #pragma unroll
    for (int i2 = 0; i2 < 4; ++i2) {
        float o0 = 0.f, o1 = 0.f;
        #pragma unroll
        for (int dy = 0; dy < 3; ++dy)
            #pragma unroll
            for (int dx = 0; dx < 3; ++dx) {
                float w = wf[dy*3+dx];
                o0 = fmaf(w, v[dy][2*i2 + dx],     o0);
                o1 = fmaf(w, v[dy][2*i2 + 1 + dx], o1);
            }
        ushort_t u0 = f2bf(o0), u1 = f2bf(o1);
        float r0 = bf2f(u0), r1 = bf2f(u1);
        s += r0 + r1; ss = fmaf(r0, r0, fmaf(r1, r1, ss));
        outp[i2] = (uint_t)u0 | ((uint_t)u1 << 16);
    }
    uint4 r; r.x = outp[0]; r.y = outp[1]; r.z = outp[2]; r.w = outp[3];
    *(uint4*)(h2 + outoff) = r;

    block_stats_atomic(s, ss, SUM2 + bc, SSQ2 + bc);
}

// ------------ temporal dw 3, 8-wide rolling window (+norm2/relu, +stats) ------
__global__ __launch_bounds__(256) void k_dwt(const ushort_t* __restrict__ h2,
                                             const float* __restrict__ wdt,
                                             ushort_t* __restrict__ h3) {
    const int tid = threadIdx.x;
    const int pos = (blockIdx.x * 256 + tid) * 8;
    const int bc  = blockIdx.y;
    const int o   = bc & (HID-1);
    const float a  = g_stats[SIS2 + bc];
    const float bb = -g_stats[SM2 + bc] * a;
    const float w0 = wdt[o*3+0], w1 = wdt[o*3+1], w2 = wdt[o*3+2];
    const ushort_t* sp = h2 + (size_t)bc * THW + pos;
    ushort_t*       op = h3 + (size_t)bc * THW + pos;

    float p[8], c[8], n[8];
    #pragma unroll
    for (int i = 0; i < 8; ++i) p[i] = 0.f;
    loadnorm8(sp,       a, bb, c);
    loadnorm8(sp + HW_, a, bb, n);

    float s = 0.f, ss = 0.f;
    #pragma unroll
    for (int t = 0; t < T_; ++t) {
        uint_t outp[4];
        #pragma unroll
        for (int i2 = 0; i2 < 4; ++i2) {
            float o0 = fmaf(w0, p[2*i2],   fmaf(w1, c[2*i2],   w2 * n[2*i2]));
            float o1 = fmaf(w0, p[2*i2+1], fmaf(w1, c[2*i2+1], w2 * n[2*i2+1]));
            ushort_t u0 = f2bf(o0), u1 = f2bf(o1);
            float r0 = bf2f(u0), r1 = bf2f(u1);
            s += r0 + r1; ss = fmaf(r0, r0, fmaf(r1, r1, ss));
            outp[i2] = (uint_t)u0 | ((uint_t)u1 << 16);
        }
        uint4 r; r.x = outp[0]; r.y = outp[1]; r.z = outp[2]; r.w = outp[3];
        *(uint4*)(op + t*HW_) = r;

        #pragma unroll
        for (int i = 0; i < 8; ++i) { p[i] = c[i]; c[i] = n[i]; }
        if (t + 2 < T_) {
            loadnorm8(sp + (t+2)*HW_, a, bb, n);
        } else {
            #pragma unroll
            for (int i = 0; i < 8; ++i) n[i] = 0.f;
        }
    }
    block_stats_atomic(s, ss, SUM3 + bc, SSQ3 + bc);
}

// ------------ SE: per-(bb,c) mean of relu(norm3(h3)) --------------------------
__global__ __launch_bounds__(256) void k_semean(const ushort_t* __restrict__ h3) {
    const int bc = blockIdx.x;
    const int tid = threadIdx.x;
    const float a  = g_stats[SIS3 + bc];
    const float bb = -g_stats[SM3 + bc] * a;
    const ushort_t* p = h3 + (size_t)bc * THW;
    float s = 0.f;
    #pragma unroll 4
    for (int i = 0; i < THW/(256*8); ++i) {
        uint4 u = *(const uint4*)(p + i*2048 + tid*8);
        uint_t w[4] = {u.x, u.y, u.z, u.w};
        #pragma unroll
        for (int j = 0; j < 4; ++j) {
            s += fmaxf(fmaf(__uint_as_float(w[j] << 16),          a, bb), 0.f);
            s += fmaxf(fmaf(__uint_as_float(w[j] & 0xffff0000u),  a, bb), 0.f);
        }
    }
    #pragma unroll
    for (int off = 32; off > 0; off >>= 1) s += __shfl_down(s, off, 64);
    __shared__ float ls[4];
    int wid = tid >> 6, lane = tid & 63;
    if (lane == 0) ls[wid] = s;
    __syncthreads();
    if (tid == 0) g_stats[SSES + bc] = (ls[0]+ls[1]+ls[2]+ls[3]) * (1.f/THW);
}

// ------------ SE MLP -> fold sigmoid scale into proj's alpha/beta -------------
__global__ __launch_bounds__(256) void k_semlp(const float* __restrict__ wse1,
                                               const float* __restrict__ wse2) {
    __shared__ float mv[HID];
    __shared__ float y1[64];
    const int bb = blockIdx.x, tid = threadIdx.x;
    mv[tid] = g_stats[SSES + bb*HID + tid];
    __syncthreads();
    if (tid < 64) {
        float acc = 0.f;
        #pragma unroll 8
        for (int c = 0; c < HID; ++c) acc = fmaf(wse1[tid*HID + c], mv[c], acc);
        y1[tid] = fmaxf(acc, 0.f);
    }
    __syncthreads();
    float z = 0.f;
    #pragma unroll
    for (int c = 0; c < 64; ++c) z = fmaf(wse2[tid*64 + c], y1[c], z);
    float se = 1.f / (1.f + expf(-z));
    const int bc = bb*HID + tid;
    float al = g_stats[SIS3 + bc] * se;
    g_stats[SAL + bc] = al;
    g_stats[SBE + bc] = -g_stats[SM3 + bc] * al;
}

// ------------ final: norm(proj) + shortcut, 2x2 maxpool, f32 out --------------
__global__ __launch_bounds__(256) void k_final(const float* __restrict__ proj,
                                               const float* __restrict__ x,
                                               float* __restrict__ out, int b0) {
    const int idx = blockIdx.x * 256 + threadIdx.x;
    const int xx = idx & 31;
    const int yy = (idx >> 5) & 31;
    const int t  = (idx >> 10) & 15;
    const int bo = idx >> 14;
    const float a  = g_stats[SISP + bo];
    const float bb = -g_stats[SMP + bo] * a;
    const size_t lbase = (size_t)bo * THW + t*HW_;
    const size_t gbase = (size_t)(b0*COUT + bo) * THW + t*HW_;

    float m = -3.4e38f;
    #pragma unroll
    for (int r = 0; r < 2; ++r) {
        size_t off = (size_t)(2*yy + r)*W_ + 2*xx;
        float2 p2 = *(const float2*)(proj + lbase + off);
        float2 x2 = *(const float2*)(x + gbase + off);
        float v0 = fmaf(p2.x, a, bb) + x2.x;
        float v1 = fmaf(p2.y, a, bb) + x2.y;
        m = fmaxf(m, fmaxf(v0, v1));
    }
    out[(size_t)b0 * COUT * T_ * 1024 + idx] = m;
}

extern "C" void kernel_launch(void* const* d_in, const int* in_sizes, int n_in,
                              void* d_out, int out_size, void* d_ws, size_t ws_size,
                              hipStream_t stream) {
    const float* x     = (const float*)d_in[0];
    const float* w1    = (const float*)d_in[1];
    const float* wdws  = (const float*)d_in[2];
    const float* wdwt  = (const float*)d_in[3];
    const float* wse1  = (const float*)d_in[4];
    const float* wse2  = (const float*)d_in[5];
    const float* wproj = (const float*)d_in[6];
    float* out = (float*)d_out;

    const size_t perb = 2ull * HID * THW * sizeof(ushort_t);   // 64 MB
    int nb = (ws_size >= 4*perb) ? 4 : (ws_size >= 2*perb) ? 2 : 1;

    k_prep<<<64, 256, 0, stream>>>(w1, wproj);

    for (int b0 = 0; b0 < B_; b0 += nb) {
        char* ws = (char*)d_ws;
        ushort_t* h1   = (ushort_t*)ws;
        ushort_t* h2   = (ushort_t*)(ws + (size_t)nb * HID*THW*2);
        ushort_t* h3   = h1;
        float*    proj = (float*)h2;

        k_zero  <<<1, 256, 0, stream>>>();
        k_expand<<<dim3(THW/64, nb), 256, 0, stream>>>(x, h1, b0);
        k_fin   <<<1, 256, 0, stream>>>(SUM1, SSQ1, SM1, SIS1, nb*HID);
        k_dws   <<<dim3(2, T_, nb*HID), 256, 0, stream>>>(h1, wdws, h2);
        k_fin   <<<1, 256, 0, stream>>>(SUM2, SSQ2, SM2, SIS2, nb*HID);
        k_dwt   <<<dim3(HW_/2048, nb*HID), 256, 0, stream>>>(h2, wdwt, h3);
        k_fin   <<<1, 256, 0, stream>>>(SUM3, SSQ3, SM3, SIS3, nb*HID);
        k_semean<<<nb*HID, 256, 0, stream>>>(h3);
        k_semlp <<<nb, 256, 0, stream>>>(wse1, wse2);
        k_proj  <<<dim3(THW/128, nb), 256, 0, stream>>>(h3, proj);
        k_fin   <<<1, 256, 0, stream>>>(SUMP, SSQP, SMP, SISP, nb*COUT);
        k_final <<<nb*COUT*T_*1024/256, 256, 0, stream>>>(proj, x, out, b0);
    }
}

// Round 7
// 447.619 us; speedup vs baseline: 3.5063x; 3.5063x over previous
//
#include <hip/hip_runtime.h>
#include <hip/hip_bf16.h>

#define B_   4
#define CIN  64
#define HID  256
#define COUT 64
#define T_   16
#define H_   64
#define W_   64
#define HW_  (H_*W_)       // 4096
#define THW  (T_*HW_)      // 65536
#define EPS  1e-5f

typedef unsigned short ushort_t;
typedef unsigned int   uint_t;
typedef short bf16x8 __attribute__((ext_vector_type(8)));
typedef float f32x4  __attribute__((ext_vector_type(4)));

// ---- stats in static device memory -------------------------------------------
#define SM1   0
#define SIS1  1024
#define SM2   2048
#define SIS2  3072
#define SM3   4096
#define SIS3  5120
#define SSES  6144
#define SAL   7168
#define SBE   8192
__device__ float g_stats[10240];
// packed bf16 weights in MFMA fragment order: [0:16384) expand, [16384:32768) proj
__device__ ushort_t g_wpack[32768];

__device__ __forceinline__ float bf2f(ushort_t u) {
    return __uint_as_float(((uint_t)u) << 16);
}
__device__ __forceinline__ ushort_t f2bf(float f) {
    uint_t u = __float_as_uint(f);
    uint_t r = u + 0x7fffu + ((u >> 16) & 1u);   // round-to-nearest-even
    return (ushort_t)(r >> 16);
}
__device__ __forceinline__ void loadnorm8(const ushort_t* p, float a, float bb,
                                          float* v) {
    uint4 u = *(const uint4*)p;
    uint_t uu[4] = {u.x, u.y, u.z, u.w};
    #pragma unroll
    for (int j = 0; j < 4; ++j) {
        v[2*j]   = fmaxf(fmaf(__uint_as_float(uu[j] << 16),         a, bb), 0.f);
        v[2*j+1] = fmaxf(fmaf(__uint_as_float(uu[j] & 0xffff0000u), a, bb), 0.f);
    }
}

// ---- pack w1 + wproj into bf16 fragment order --------------------------------
__global__ __launch_bounds__(256) void k_prep(const float* __restrict__ w1,
                                              const float* __restrict__ wproj) {
    int idx = blockIdx.x*256 + threadIdx.x;        // 0..16383
    {
        int j = idx & 7, lane = (idx>>3) & 63, ot = (idx>>9) & 3;
        int ks = (idx>>11) & 1, wv = idx >> 12;
        int ln = lane & 15, q = lane >> 4;
        int o = wv*64 + ot*16 + ln, k = ks*32 + q*8 + j;
        g_wpack[idx] = f2bf(w1[o*CIN + k]);
    }
    {
        int j = idx & 7, lane = (idx>>3) & 63, ot = (idx>>9) & 3, kg = idx >> 11;
        int ln = lane & 15, q = lane >> 4;
        int o = ot*16 + ln, k = kg*32 + q*8 + j;
        g_wpack[16384 + idx] = f2bf(wproj[o*HID + k]);
    }
}

// ============ expand 1x1 via MFMA (A from packed global) ======================
__global__ __launch_bounds__(256) void k_expand(const float* __restrict__ x,
                                                ushort_t* __restrict__ h1, int b0) {
    __shared__ ushort_t Bs[64*72];       // B[k][n], stride 72, rotated cols
    const int tid = threadIdx.x;
    const int bb  = blockIdx.y, gb = b0 + bb;
    const int pos0 = blockIdx.x * 64;
    const int lane = tid & 63, wv = tid >> 6;
    const int q = lane >> 4, ln = lane & 15;

    bf16x8 af[2][4];
    #pragma unroll
    for (int ks = 0; ks < 2; ++ks)
        #pragma unroll
        for (int ot = 0; ot < 4; ++ot)
            af[ks][ot] = *(const bf16x8*)&g_wpack[(((wv*2+ks)*4+ot)<<9) + lane*8];

    #pragma unroll
    for (int i = 0; i < 16; ++i) {
        int linear = i*256 + tid;
        int k = linear >> 6, n = linear & 63;
        float v = x[(size_t)(gb*CIN + k) * THW + pos0 + n];
        Bs[k*72 + ((n + 16*((k>>3)&3)) & 63)] = f2bf(v);
    }
    __syncthreads();

    f32x4 acc[4][4];
    #pragma unroll
    for (int i = 0; i < 4; ++i)
        #pragma unroll
        for (int j = 0; j < 4; ++j)
            acc[i][j] = (f32x4){0.f,0.f,0.f,0.f};

    #pragma unroll
    for (int ks = 0; ks < 2; ++ks) {
        bf16x8 bfr[4];
        #pragma unroll
        for (int nt = 0; nt < 4; ++nt) {
            union { short s[8]; bf16x8 v; } bu;
            #pragma unroll
            for (int j = 0; j < 8; ++j) {
                int k = ks*32 + q*8 + j;
                int nn = (nt*16 + ln + 16*((k>>3)&3)) & 63;
                bu.s[j] = (short)Bs[k*72 + nn];
            }
            bfr[nt] = bu.v;
        }
        #pragma unroll
        for (int ot = 0; ot < 4; ++ot)
            #pragma unroll
            for (int nt = 0; nt < 4; ++nt)
                acc[ot][nt] = __builtin_amdgcn_mfma_f32_16x16x32_bf16(
                    af[ks][ot], bfr[nt], acc[ot][nt], 0, 0, 0);
    }

    #pragma unroll
    for (int ot = 0; ot < 4; ++ot)
        #pragma unroll
        for (int nt = 0; nt < 4; ++nt)
            #pragma unroll
            for (int r = 0; r < 4; ++r) {
                int o = wv*64 + ot*16 + q*4 + r;
                int n = nt*16 + ln;
                h1[((size_t)bb*HID + o)*THW + pos0 + n] = f2bf(acc[ot][nt][r]);
            }
}

// ============ proj 1x1 via MFMA (A from packed global, norm3+relu+SE in B) ====
__global__ __launch_bounds__(256) void k_proj(const ushort_t* __restrict__ h3,
                                              float* __restrict__ proj) {
    __shared__ ushort_t Bs[64*136];      // B[klocal][n], stride 136, rotated cols
    const int tid = threadIdx.x;
    const int bb  = blockIdx.y;
    const int pos0 = blockIdx.x * 128;
    const int lane = tid & 63, wv = tid >> 6;
    const int q = lane >> 4, ln = lane & 15;

    f32x4 acc[4][2];
    #pragma unroll
    for (int i = 0; i < 4; ++i) {
        acc[i][0] = (f32x4){0.f,0.f,0.f,0.f};
        acc[i][1] = (f32x4){0.f,0.f,0.f,0.f};
    }

    for (int kc = 0; kc < 4; ++kc) {
        #pragma unroll
        for (int i = 0; i < 32; ++i) {
            int linear = i*256 + tid;
            int kl = linear >> 7, n = linear & 127;
            int ch = bb*HID + kc*64 + kl;
            float raw = bf2f(h3[(size_t)ch * THW + pos0 + n]);
            float v = fmaxf(fmaf(raw, g_stats[SAL + ch], g_stats[SBE + ch]), 0.f);
            Bs[kl*136 + ((n + 16*((kl>>3)&7)) & 127)] = f2bf(v);
        }
        __syncthreads();

        #pragma unroll
        for (int ks = 0; ks < 2; ++ks) {
            int kg = kc*2 + ks;
            bf16x8 af[4];
            #pragma unroll
            for (int ot = 0; ot < 4; ++ot)
                af[ot] = *(const bf16x8*)&g_wpack[16384 + ((kg*4+ot)<<9) + lane*8];
            bf16x8 bfr[2];
            #pragma unroll
            for (int nt = 0; nt < 2; ++nt) {
                union { short s[8]; bf16x8 v; } bu;
                #pragma unroll
                for (int j = 0; j < 8; ++j) {
                    int kl = ks*32 + q*8 + j;
                    int nn = (wv*32 + nt*16 + ln + 16*((kl>>3)&7)) & 127;
                    bu.s[j] = (short)Bs[kl*136 + nn];
                }
                bfr[nt] = bu.v;
            }
            #pragma unroll
            for (int ot = 0; ot < 4; ++ot)
                #pragma unroll
                for (int nt = 0; nt < 2; ++nt)
                    acc[ot][nt] = __builtin_amdgcn_mfma_f32_16x16x32_bf16(
                        af[ot], bfr[nt], acc[ot][nt], 0, 0, 0);
        }
        __syncthreads();
    }

    #pragma unroll
    for (int ot = 0; ot < 4; ++ot)
        #pragma unroll
        for (int nt = 0; nt < 2; ++nt)
            #pragma unroll
            for (int r = 0; r < 4; ++r) {
                int o = ot*16 + q*4 + r;
                int n = wv*32 + nt*16 + ln;
                proj[((size_t)bb*COUT + o)*THW + pos0 + n] = acc[ot][nt][r];
            }
}

// ---------------- per-(bb,c) mean / inv_sd over THW, bf16 source --------------
__global__ __launch_bounds__(256) void k_stats_bf16(const ushort_t* __restrict__ src,
                                                    int moff, int isoff) {
    const int bc = blockIdx.x;
    const int tid = threadIdx.x;
    const ushort_t* p = src + (size_t)bc * THW;
    float s = 0.f, ss = 0.f;
    #pragma unroll 4
    for (int i = 0; i < THW/(256*8); ++i) {       // 32 iters, 16B/lane
        uint4 u = *(const uint4*)(p + i*2048 + tid*8);
        uint_t w[4] = {u.x, u.y, u.z, u.w};
        #pragma unroll
        for (int j = 0; j < 4; ++j) {
            float f0 = __uint_as_float(w[j] << 16);
            float f1 = __uint_as_float(w[j] & 0xffff0000u);
            s += f0; ss = fmaf(f0, f0, ss);
            s += f1; ss = fmaf(f1, f1, ss);
        }
    }
    #pragma unroll
    for (int off = 32; off > 0; off >>= 1) {
        s  += __shfl_down(s,  off, 64);
        ss += __shfl_down(ss, off, 64);
    }
    __shared__ float ls[4], lss[4];
    int wid = tid >> 6, lane = tid & 63;
    if (lane == 0) { ls[wid] = s; lss[wid] = ss; }
    __syncthreads();
    if (tid == 0) {
        float st  = ls[0]+ls[1]+ls[2]+ls[3];
        float sst = lss[0]+lss[1]+lss[2]+lss[3];
        float m = st * (1.f/THW);
        float v = sst * (1.f/THW) - m*m;
        g_stats[moff  + bc] = m;
        g_stats[isoff + bc] = 1.f / sqrtf(v + EPS);
    }
}

// ---- h3 stats + SE relu-mean in ONE kernel (channel self-contained) ----------
__global__ __launch_bounds__(256) void k_stats3se(const ushort_t* __restrict__ h3) {
    const int bc = blockIdx.x;
    const int tid = threadIdx.x;
    const ushort_t* p = h3 + (size_t)bc * THW;
    float s = 0.f, ss = 0.f;
    #pragma unroll 4
    for (int i = 0; i < THW/(256*8); ++i) {
        uint4 u = *(const uint4*)(p + i*2048 + tid*8);
        uint_t w[4] = {u.x, u.y, u.z, u.w};
        #pragma unroll
        for (int j = 0; j < 4; ++j) {
            float f0 = __uint_as_float(w[j] << 16);
            float f1 = __uint_as_float(w[j] & 0xffff0000u);
            s += f0; ss = fmaf(f0, f0, ss);
            s += f1; ss = fmaf(f1, f1, ss);
        }
    }
    #pragma unroll
    for (int off = 32; off > 0; off >>= 1) {
        s  += __shfl_down(s,  off, 64);
        ss += __shfl_down(ss, off, 64);
    }
    __shared__ float ls[4], lss[4];
    __shared__ float sa, sb;
    int wid = tid >> 6, lane = tid & 63;
    if (lane == 0) { ls[wid] = s; lss[wid] = ss; }
    __syncthreads();
    if (tid == 0) {
        float st  = ls[0]+ls[1]+ls[2]+ls[3];
        float sst = lss[0]+lss[1]+lss[2]+lss[3];
        float m = st * (1.f/THW);
        float v = sst * (1.f/THW) - m*m;
        float is = 1.f / sqrtf(v + EPS);
        g_stats[SM3  + bc] = m;
        g_stats[SIS3 + bc] = is;
        sa = is; sb = -m * is;
    }
    __syncthreads();
    // pass 2: relu-mean (re-read, L2-favorable)
    const float a = sa, bb = sb;
    float s2 = 0.f;
    #pragma unroll 4
    for (int i = 0; i < THW/(256*8); ++i) {
        uint4 u = *(const uint4*)(p + i*2048 + tid*8);
        uint_t w[4] = {u.x, u.y, u.z, u.w};
        #pragma unroll
        for (int j = 0; j < 4; ++j) {
            s2 += fmaxf(fmaf(__uint_as_float(w[j] << 16),         a, bb), 0.f);
            s2 += fmaxf(fmaf(__uint_as_float(w[j] & 0xffff0000u), a, bb), 0.f);
        }
    }
    #pragma unroll
    for (int off = 32; off > 0; off >>= 1) s2 += __shfl_down(s2, off, 64);
    if (lane == 0) ls[wid] = s2;
    __syncthreads();
    if (tid == 0) g_stats[SSES + bc] = (ls[0]+ls[1]+ls[2]+ls[3]) * (1.f/THW);
}

// ------------ spatial dw 3x3, 8-wide (+TIM, +norm1/relu) ----------------------
__global__ __launch_bounds__(256) void k_dws(const ushort_t* __restrict__ h1,
                                             const float* __restrict__ wdw,
                                             ushort_t* __restrict__ h2) {
    const int tid = threadIdx.x;
    const int x0  = (tid & 7) * 8;
    const int y   = blockIdx.x * 32 + (tid >> 3);
    const int t   = blockIdx.y;
    const int bc  = blockIdx.z;
    const int o   = bc & (HID-1);
    const size_t outoff = (size_t)bc * THW + t*HW_ + y*W_ + x0;

    int ts = t; bool zero = false;
    if (o < 32)       { ts = t + 1; if (ts >= T_) zero = true; }
    else if (o < 64)  { zero = true; }
    if (zero) {
        uint4 z = {0u,0u,0u,0u};
        *(uint4*)(h2 + outoff) = z;
        return;
    }

    const float a  = g_stats[SIS1 + bc];
    const float bb = -g_stats[SM1 + bc] * a;
    const ushort_t* sp = h1 + (size_t)bc * THW + ts*HW_;

    float wf[9];
    #pragma unroll
    for (int k = 0; k < 9; ++k) wf[k] = wdw[o*9 + k];

    float v[3][10];
    #pragma unroll
    for (int dy = 0; dy < 3; ++dy) {
        int yy = y + dy - 1;
        if (yy < 0 || yy >= H_) {
            #pragma unroll
            for (int j = 0; j < 10; ++j) v[dy][j] = 0.f;
        } else {
            const ushort_t* rp = sp + yy*W_;
            loadnorm8(rp + x0, a, bb, &v[dy][1]);
            v[dy][0] = (x0 == 0)  ? 0.f : fmaxf(fmaf(bf2f(rp[x0-1]), a, bb), 0.f);
            v[dy][9] = (x0 == 56) ? 0.f : fmaxf(fmaf(bf2f(rp[x0+8]), a, bb), 0.f);
        }
    }

    uint_t outp[4];
    #pragma unroll
    for (int i2 = 0; i2 < 4; ++i2) {
        float o0 = 0.f, o1 = 0.f;
        #pragma unroll
        for (int dy = 0; dy < 3; ++dy)
            #pragma unroll
            for (int dx = 0; dx < 3; ++dx) {
                float w = wf[dy*3+dx];
                o0 = fmaf(w, v[dy][2*i2 + dx],     o0);
                o1 = fmaf(w, v[dy][2*i2 + 1 + dx], o1);
            }
        outp[i2] = (uint_t)f2bf(o0) | ((uint_t)f2bf(o1) << 16);
    }
    uint4 r; r.x = outp[0]; r.y = outp[1]; r.z = outp[2]; r.w = outp[3];
    *(uint4*)(h2 + outoff) = r;
}

// ------------ temporal dw 3, 8-wide rolling window (+norm2/relu) --------------
__global__ __launch_bounds__(256) void k_dwt(const ushort_t* __restrict__ h2,
                                             const float* __restrict__ wdt,
                                             ushort_t* __restrict__ h3) {
    const int tid = threadIdx.x;
    const int pos = (blockIdx.x * 256 + tid) * 8;
    const int bc  = blockIdx.y;
    const int o   = bc & (HID-1);
    const float a  = g_stats[SIS2 + bc];
    const float bb = -g_stats[SM2 + bc] * a;
    const float w0 = wdt[o*3+0], w1 = wdt[o*3+1], w2 = wdt[o*3+2];
    const ushort_t* sp = h2 + (size_t)bc * THW + pos;
    ushort_t*       op = h3 + (size_t)bc * THW + pos;

    float p[8], c[8], n[8];
    #pragma unroll
    for (int i = 0; i < 8; ++i) p[i] = 0.f;
    loadnorm8(sp,       a, bb, c);
    loadnorm8(sp + HW_, a, bb, n);

    #pragma unroll
    for (int t = 0; t < T_; ++t) {
        uint_t outp[4];
        #pragma unroll
        for (int i2 = 0; i2 < 4; ++i2) {
            float o0 = fmaf(w0, p[2*i2],   fmaf(w1, c[2*i2],   w2 * n[2*i2]));
            float o1 = fmaf(w0, p[2*i2+1], fmaf(w1, c[2*i2+1], w2 * n[2*i2+1]));
            outp[i2] = (uint_t)f2bf(o0) | ((uint_t)f2bf(o1) << 16);
        }
        uint4 r; r.x = outp[0]; r.y = outp[1]; r.z = outp[2]; r.w = outp[3];
        *(uint4*)(op + t*HW_) = r;

        #pragma unroll
        for (int i = 0; i < 8; ++i) { p[i] = c[i]; c[i] = n[i]; }
        if (t + 2 < T_) {
            loadnorm8(sp + (t+2)*HW_, a, bb, n);
        } else {
            #pragma unroll
            for (int i = 0; i < 8; ++i) n[i] = 0.f;
        }
    }
}

// ------------ SE MLP -> fold sigmoid scale into proj's alpha/beta -------------
__global__ __launch_bounds__(256) void k_semlp(const float* __restrict__ wse1,
                                               const float* __restrict__ wse2) {
    __shared__ float mv[HID];
    __shared__ float y1[64];
    const int bb = blockIdx.x, tid = threadIdx.x;
    mv[tid] = g_stats[SSES + bb*HID + tid];
    __syncthreads();
    if (tid < 64) {
        float acc = 0.f;
        #pragma unroll 8
        for (int c = 0; c < HID; ++c) acc = fmaf(wse1[tid*HID + c], mv[c], acc);
        y1[tid] = fmaxf(acc, 0.f);
    }
    __syncthreads();
    float z = 0.f;
    #pragma unroll
    for (int c = 0; c < 64; ++c) z = fmaf(wse2[tid*64 + c], y1[c], z);
    float se = 1.f / (1.f + expf(-z));
    const int bc = bb*HID + tid;
    float al = g_stats[SIS3 + bc] * se;
    g_stats[SAL + bc] = al;
    g_stats[SBE + bc] = -g_stats[SM3 + bc] * al;
}

// ------------ final fused: proj stats + norm + shortcut + maxpool -------------
// one block per (bb,o) channel; 1024 threads; two passes (2nd is L2-favorable)
__global__ __launch_bounds__(1024) void k_final(const float* __restrict__ proj,
                                                const float* __restrict__ x,
                                                float* __restrict__ out, int b0) {
    const int bo  = blockIdx.x;                    // local bb*COUT + o
    const int tid = threadIdx.x;
    const float* p = proj + (size_t)bo * THW;

    // pass 1: moments over THW fp32
    float s = 0.f, ss = 0.f;
    #pragma unroll
    for (int i = 0; i < THW/(1024*4); ++i) {       // 16 iters
        float4 u = *(const float4*)(p + i*4096 + tid*4);
        s += u.x; ss = fmaf(u.x, u.x, ss);
        s += u.y; ss = fmaf(u.y, u.y, ss);
        s += u.z; ss = fmaf(u.z, u.z, ss);
        s += u.w; ss = fmaf(u.w, u.w, ss);
    }
    #pragma unroll
    for (int off = 32; off > 0; off >>= 1) {
        s  += __shfl_down(s,  off, 64);
        ss += __shfl_down(ss, off, 64);
    }
    __shared__ float ls[16], lss[16];
    __shared__ float sa, sb;
    int wid = tid >> 6, lane = tid & 63;
    if (lane == 0) { ls[wid] = s; lss[wid] = ss; }
    __syncthreads();
    if (tid == 0) {
        float st = 0.f, sst = 0.f;
        #pragma unroll
        for (int i = 0; i < 16; ++i) { st += ls[i]; sst += lss[i]; }
        float m = st * (1.f/THW);
        float v = sst * (1.f/THW) - m*m;
        float is = 1.f / sqrtf(v + EPS);
        sa = is; sb = -m * is;
    }
    __syncthreads();
    const float a = sa, bb = sb;

    // pass 2: norm + residual + 2x2 maxpool; 16384 outputs / block
    const size_t gbase = (size_t)(b0*COUT + bo) * THW;
    float* op = out + (size_t)(b0*COUT + bo) * (T_*1024);
    #pragma unroll
    for (int i = 0; i < 16; ++i) {
        int idx = i*1024 + tid;                    // 0..16383
        int xx = idx & 31, yy = (idx >> 5) & 31, t = idx >> 10;
        float m = -3.4e38f;
        #pragma unroll
        for (int r = 0; r < 2; ++r) {
            size_t off = (size_t)t*HW_ + (size_t)(2*yy + r)*W_ + 2*xx;
            float2 p2 = *(const float2*)(p + off);
            float2 x2 = *(const float2*)(x + gbase + off);
            float v0 = fmaf(p2.x, a, bb) + x2.x;
            float v1 = fmaf(p2.y, a, bb) + x2.y;
            m = fmaxf(m, fmaxf(v0, v1));
        }
        op[idx] = m;
    }
}

extern "C" void kernel_launch(void* const* d_in, const int* in_sizes, int n_in,
                              void* d_out, int out_size, void* d_ws, size_t ws_size,
                              hipStream_t stream) {
    const float* x     = (const float*)d_in[0];
    const float* w1    = (const float*)d_in[1];
    const float* wdws  = (const float*)d_in[2];
    const float* wdwt  = (const float*)d_in[3];
    const float* wse1  = (const float*)d_in[4];
    const float* wse2  = (const float*)d_in[5];
    const float* wproj = (const float*)d_in[6];
    float* out = (float*)d_out;

    const size_t perb = 2ull * HID * THW * sizeof(ushort_t);   // 64 MB
    int nb = (ws_size >= 4*perb) ? 4 : (ws_size >= 2*perb) ? 2 : 1;

    k_prep<<<64, 256, 0, stream>>>(w1, wproj);

    for (int b0 = 0; b0 < B_; b0 += nb) {
        char* ws = (char*)d_ws;
        ushort_t* h1   = (ushort_t*)ws;
        ushort_t* h2   = (ushort_t*)(ws + (size_t)nb * HID*THW*2);
        ushort_t* h3   = h1;
        float*    proj = (float*)h2;

        k_expand    <<<dim3(THW/64, nb), 256, 0, stream>>>(x, h1, b0);
        k_stats_bf16<<<nb*HID, 256, 0, stream>>>(h1, SM1, SIS1);
        k_dws       <<<dim3(2, T_, nb*HID), 256, 0, stream>>>(h1, wdws, h2);
        k_stats_bf16<<<nb*HID, 256, 0, stream>>>(h2, SM2, SIS2);
        k_dwt       <<<dim3(HW_/2048, nb*HID), 256, 0, stream>>>(h2, wdwt, h3);
        k_stats3se  <<<nb*HID, 256, 0, stream>>>(h3);
        k_semlp     <<<nb, 256, 0, stream>>>(wse1, wse2);
        k_proj      <<<dim3(THW/128, nb), 256, 0, stream>>>(h3, proj);
        k_final     <<<nb*COUT, 1024, 0, stream>>>(proj, x, out, b0);
    }
}

// Round 8
// 418.770 us; speedup vs baseline: 3.7478x; 1.0689x over previous
//
#include <hip/hip_runtime.h>
#include <hip/hip_bf16.h>

#define B_   4
#define CIN  64
#define HID  256
#define COUT 64
#define T_   16
#define H_   64
#define W_   64
#define HW_  (H_*W_)       // 4096
#define THW  (T_*HW_)      // 65536
#define EPS  1e-5f

typedef unsigned short ushort_t;
typedef unsigned int   uint_t;
typedef short bf16x8 __attribute__((ext_vector_type(8)));
typedef float f32x4  __attribute__((ext_vector_type(4)));

// ---- stats in static device memory -------------------------------------------
#define SM1   0
#define SIS1  1024
#define SM2   2048
#define SIS2  3072
#define SM3   4096
#define SIS3  5120
#define SSES  6144
#define SAL   7168
#define SBE   8192
__device__ float g_stats[10240];
// packed bf16 weights in MFMA fragment order: [0:16384) expand, [16384:32768) proj
__device__ ushort_t g_wpack[32768];

__device__ __forceinline__ float bf2f(ushort_t u) {
    return __uint_as_float(((uint_t)u) << 16);
}
__device__ __forceinline__ ushort_t f2bf(float f) {
    uint_t u = __float_as_uint(f);
    uint_t r = u + 0x7fffu + ((u >> 16) & 1u);   // round-to-nearest-even
    return (ushort_t)(r >> 16);
}
__device__ __forceinline__ void loadnorm8(const ushort_t* p, float a, float bb,
                                          float* v) {
    uint4 u = *(const uint4*)p;
    uint_t uu[4] = {u.x, u.y, u.z, u.w};
    #pragma unroll
    for (int j = 0; j < 4; ++j) {
        v[2*j]   = fmaxf(fmaf(__uint_as_float(uu[j] << 16),         a, bb), 0.f);
        v[2*j+1] = fmaxf(fmaf(__uint_as_float(uu[j] & 0xffff0000u), a, bb), 0.f);
    }
}

// ---- pack w1 + wproj into bf16 fragment order --------------------------------
__global__ __launch_bounds__(256) void k_prep(const float* __restrict__ w1,
                                              const float* __restrict__ wproj) {
    int idx = blockIdx.x*256 + threadIdx.x;        // 0..16383
    {
        int j = idx & 7, lane = (idx>>3) & 63, ot = (idx>>9) & 3;
        int ks = (idx>>11) & 1, wv = idx >> 12;
        int ln = lane & 15, q = lane >> 4;
        int o = wv*64 + ot*16 + ln, k = ks*32 + q*8 + j;
        g_wpack[idx] = f2bf(w1[o*CIN + k]);
    }
    {
        int j = idx & 7, lane = (idx>>3) & 63, ot = (idx>>9) & 3, kg = idx >> 11;
        int ln = lane & 15, q = lane >> 4;
        int o = ot*16 + ln, k = kg*32 + q*8 + j;
        g_wpack[16384 + idx] = f2bf(wproj[o*HID + k]);
    }
}

// ============ expand 1x1 via MFMA (A from packed global) ======================
__global__ __launch_bounds__(256) void k_expand(const float* __restrict__ x,
                                                ushort_t* __restrict__ h1, int b0) {
    __shared__ ushort_t Bs[64*72];       // B[k][n], stride 72, rotated cols
    const int tid = threadIdx.x;
    const int bb  = blockIdx.y, gb = b0 + bb;
    const int pos0 = blockIdx.x * 64;
    const int lane = tid & 63, wv = tid >> 6;
    const int q = lane >> 4, ln = lane & 15;

    bf16x8 af[2][4];
    #pragma unroll
    for (int ks = 0; ks < 2; ++ks)
        #pragma unroll
        for (int ot = 0; ot < 4; ++ot)
            af[ks][ot] = *(const bf16x8*)&g_wpack[(((wv*2+ks)*4+ot)<<9) + lane*8];

    #pragma unroll
    for (int i = 0; i < 16; ++i) {
        int linear = i*256 + tid;
        int k = linear >> 6, n = linear & 63;
        float v = x[(size_t)(gb*CIN + k) * THW + pos0 + n];
        Bs[k*72 + ((n + 16*((k>>3)&3)) & 63)] = f2bf(v);
    }
    __syncthreads();

    f32x4 acc[4][4];
    #pragma unroll
    for (int i = 0; i < 4; ++i)
        #pragma unroll
        for (int j = 0; j < 4; ++j)
            acc[i][j] = (f32x4){0.f,0.f,0.f,0.f};

    #pragma unroll
    for (int ks = 0; ks < 2; ++ks) {
        bf16x8 bfr[4];
        #pragma unroll
        for (int nt = 0; nt < 4; ++nt) {
            union { short s[8]; bf16x8 v; } bu;
            #pragma unroll
            for (int j = 0; j < 8; ++j) {
                int k = ks*32 + q*8 + j;
                int nn = (nt*16 + ln + 16*((k>>3)&3)) & 63;
                bu.s[j] = (short)Bs[k*72 + nn];
            }
            bfr[nt] = bu.v;
        }
        #pragma unroll
        for (int ot = 0; ot < 4; ++ot)
            #pragma unroll
            for (int nt = 0; nt < 4; ++nt)
                acc[ot][nt] = __builtin_amdgcn_mfma_f32_16x16x32_bf16(
                    af[ks][ot], bfr[nt], acc[ot][nt], 0, 0, 0);
    }

    #pragma unroll
    for (int ot = 0; ot < 4; ++ot)
        #pragma unroll
        for (int nt = 0; nt < 4; ++nt)
            #pragma unroll
            for (int r = 0; r < 4; ++r) {
                int o = wv*64 + ot*16 + q*4 + r;
                int n = nt*16 + ln;
                h1[((size_t)bb*HID + o)*THW + pos0 + n] = f2bf(acc[ot][nt][r]);
            }
}

// ============ proj 1x1 via MFMA (A from packed global, norm3+relu+SE in B) ====
__global__ __launch_bounds__(256) void k_proj(const ushort_t* __restrict__ h3,
                                              float* __restrict__ proj) {
    __shared__ ushort_t Bs[64*136];      // B[klocal][n], stride 136, rotated cols
    const int tid = threadIdx.x;
    const int bb  = blockIdx.y;
    const int pos0 = blockIdx.x * 128;
    const int lane = tid & 63, wv = tid >> 6;
    const int q = lane >> 4, ln = lane & 15;

    f32x4 acc[4][2];
    #pragma unroll
    for (int i = 0; i < 4; ++i) {
        acc[i][0] = (f32x4){0.f,0.f,0.f,0.f};
        acc[i][1] = (f32x4){0.f,0.f,0.f,0.f};
    }

    for (int kc = 0; kc < 4; ++kc) {
        #pragma unroll
        for (int i = 0; i < 32; ++i) {
            int linear = i*256 + tid;
            int kl = linear >> 7, n = linear & 127;
            int ch = bb*HID + kc*64 + kl;
            float raw = bf2f(h3[(size_t)ch * THW + pos0 + n]);
            float v = fmaxf(fmaf(raw, g_stats[SAL + ch], g_stats[SBE + ch]), 0.f);
            Bs[kl*136 + ((n + 16*((kl>>3)&7)) & 127)] = f2bf(v);
        }
        __syncthreads();

        #pragma unroll
        for (int ks = 0; ks < 2; ++ks) {
            int kg = kc*2 + ks;
            bf16x8 af[4];
            #pragma unroll
            for (int ot = 0; ot < 4; ++ot)
                af[ot] = *(const bf16x8*)&g_wpack[16384 + ((kg*4+ot)<<9) + lane*8];
            bf16x8 bfr[2];
            #pragma unroll
            for (int nt = 0; nt < 2; ++nt) {
                union { short s[8]; bf16x8 v; } bu;
                #pragma unroll
                for (int j = 0; j < 8; ++j) {
                    int kl = ks*32 + q*8 + j;
                    int nn = (wv*32 + nt*16 + ln + 16*((kl>>3)&7)) & 127;
                    bu.s[j] = (short)Bs[kl*136 + nn];
                }
                bfr[nt] = bu.v;
            }
            #pragma unroll
            for (int ot = 0; ot < 4; ++ot)
                #pragma unroll
                for (int nt = 0; nt < 2; ++nt)
                    acc[ot][nt] = __builtin_amdgcn_mfma_f32_16x16x32_bf16(
                        af[ot], bfr[nt], acc[ot][nt], 0, 0, 0);
        }
        __syncthreads();
    }

    #pragma unroll
    for (int ot = 0; ot < 4; ++ot)
        #pragma unroll
        for (int nt = 0; nt < 2; ++nt)
            #pragma unroll
            for (int r = 0; r < 4; ++r) {
                int o = ot*16 + q*4 + r;
                int n = wv*32 + nt*16 + ln;
                proj[((size_t)bb*COUT + o)*THW + pos0 + n] = acc[ot][nt][r];
            }
}

// ---------------- per-(bb,c) mean / inv_sd over THW, bf16 source (h1 only) ----
__global__ __launch_bounds__(256) void k_stats_bf16(const ushort_t* __restrict__ src,
                                                    int moff, int isoff) {
    const int bc = blockIdx.x;
    const int tid = threadIdx.x;
    const ushort_t* p = src + (size_t)bc * THW;
    float s = 0.f, ss = 0.f;
    #pragma unroll 4
    for (int i = 0; i < THW/(256*8); ++i) {       // 32 iters, 16B/lane
        uint4 u = *(const uint4*)(p + i*2048 + tid*8);
        uint_t w[4] = {u.x, u.y, u.z, u.w};
        #pragma unroll
        for (int j = 0; j < 4; ++j) {
            float f0 = __uint_as_float(w[j] << 16);
            float f1 = __uint_as_float(w[j] & 0xffff0000u);
            s += f0; ss = fmaf(f0, f0, ss);
            s += f1; ss = fmaf(f1, f1, ss);
        }
    }
    #pragma unroll
    for (int off = 32; off > 0; off >>= 1) {
        s  += __shfl_down(s,  off, 64);
        ss += __shfl_down(ss, off, 64);
    }
    __shared__ float ls[4], lss[4];
    int wid = tid >> 6, lane = tid & 63;
    if (lane == 0) { ls[wid] = s; lss[wid] = ss; }
    __syncthreads();
    if (tid == 0) {
        float st  = ls[0]+ls[1]+ls[2]+ls[3];
        float sst = lss[0]+lss[1]+lss[2]+lss[3];
        float m = st * (1.f/THW);
        float v = sst * (1.f/THW) - m*m;
        g_stats[moff  + bc] = m;
        g_stats[isoff + bc] = 1.f / sqrtf(v + EPS);
    }
}

// ------------ spatial dw 3x3, 8-wide, ONE BLOCK PER CHANNEL (+stats2) ---------
// 256 thr; loops t (16) x y-half (2); writes SM2/SIS2 at end — no atomics
__global__ __launch_bounds__(256) void k_dws(const ushort_t* __restrict__ h1,
                                             const float* __restrict__ wdw,
                                             ushort_t* __restrict__ h2) {
    const int tid = threadIdx.x;
    const int bc  = blockIdx.x;
    const int o   = bc & (HID-1);
    const int x0  = (tid & 7) * 8;
    const int yb  = tid >> 3;                     // 0..31

    const float a  = g_stats[SIS1 + bc];
    const float bb = -g_stats[SM1 + bc] * a;
    const ushort_t* cbase = h1 + (size_t)bc * THW;
    ushort_t*       obase = h2 + (size_t)bc * THW;
    const bool zeroall = (o >= 32 && o < 64);

    float wf[9];
    #pragma unroll
    for (int k = 0; k < 9; ++k) wf[k] = wdw[o*9 + k];

    float s = 0.f, ss = 0.f;
    for (int t = 0; t < T_; ++t) {
        int ts = t; bool zero = zeroall;
        if (o < 32) { ts = t + 1; if (ts >= T_) zero = true; }
        const ushort_t* sp = cbase + ts*HW_;
        #pragma unroll
        for (int half = 0; half < 2; ++half) {
            const int y = half*32 + yb;
            ushort_t* op = obase + t*HW_ + y*W_ + x0;
            if (zero) {
                uint4 z = {0u,0u,0u,0u};
                *(uint4*)op = z;
            } else {
                float v[3][10];
                #pragma unroll
                for (int dy = 0; dy < 3; ++dy) {
                    int yy = y + dy - 1;
                    if (yy < 0 || yy >= H_) {
                        #pragma unroll
                        for (int j = 0; j < 10; ++j) v[dy][j] = 0.f;
                    } else {
                        const ushort_t* rp = sp + yy*W_;
                        loadnorm8(rp + x0, a, bb, &v[dy][1]);
                        v[dy][0] = (x0 == 0)  ? 0.f : fmaxf(fmaf(bf2f(rp[x0-1]), a, bb), 0.f);
                        v[dy][9] = (x0 == 56) ? 0.f : fmaxf(fmaf(bf2f(rp[x0+8]), a, bb), 0.f);
                    }
                }
                uint_t outp[4];
                #pragma unroll
                for (int i2 = 0; i2 < 4; ++i2) {
                    float o0 = 0.f, o1 = 0.f;
                    #pragma unroll
                    for (int dy = 0; dy < 3; ++dy)
                        #pragma unroll
                        for (int dx = 0; dx < 3; ++dx) {
                            float w = wf[dy*3+dx];
                            o0 = fmaf(w, v[dy][2*i2 + dx],     o0);
                            o1 = fmaf(w, v[dy][2*i2 + 1 + dx], o1);
                        }
                    ushort_t u0 = f2bf(o0), u1 = f2bf(o1);
                    float r0 = bf2f(u0), r1 = bf2f(u1);
                    s += r0 + r1; ss = fmaf(r0, r0, fmaf(r1, r1, ss));
                    outp[i2] = (uint_t)u0 | ((uint_t)u1 << 16);
                }
                uint4 r; r.x = outp[0]; r.y = outp[1]; r.z = outp[2]; r.w = outp[3];
                *(uint4*)op = r;
            }
        }
    }

    // block-wide stats (exact: block owns the whole channel)
    #pragma unroll
    for (int m = 32; m > 0; m >>= 1) {
        s  += __shfl_xor(s,  m);
        ss += __shfl_xor(ss, m);
    }
    __shared__ float ls[4], lss[4];
    int wid = tid >> 6, lane = tid & 63;
    if (lane == 0) { ls[wid] = s; lss[wid] = ss; }
    __syncthreads();
    if (tid == 0) {
        float st  = ls[0]+ls[1]+ls[2]+ls[3];
        float sst = lss[0]+lss[1]+lss[2]+lss[3];
        float m = st * (1.f/THW);
        float v = sst * (1.f/THW) - m*m;
        g_stats[SM2  + bc] = m;
        g_stats[SIS2 + bc] = 1.f / sqrtf(v + EPS);
    }
}

// ------------ temporal dw 3, ONE BLOCK PER CHANNEL (+stats3 +SE mean) ---------
// 512 thr x 8 pos = full 4096 slice; outputs kept in registers for SE pass
__global__ __launch_bounds__(512) void k_dwt(const ushort_t* __restrict__ h2,
                                             const float* __restrict__ wdt,
                                             ushort_t* __restrict__ h3) {
    const int tid = threadIdx.x;                  // 0..511
    const int pos = tid * 8;
    const int bc  = blockIdx.x;
    const int o   = bc & (HID-1);
    const float a  = g_stats[SIS2 + bc];
    const float bb = -g_stats[SM2 + bc] * a;
    const float w0 = wdt[o*3+0], w1 = wdt[o*3+1], w2 = wdt[o*3+2];
    const ushort_t* sp = h2 + (size_t)bc * THW + pos;
    ushort_t*       op = h3 + (size_t)bc * THW + pos;

    float p[8], c[8], n[8];
    #pragma unroll
    for (int i = 0; i < 8; ++i) p[i] = 0.f;
    loadnorm8(sp,       a, bb, c);
    loadnorm8(sp + HW_, a, bb, n);

    uint4 keep[16];
    float s = 0.f, ss = 0.f;
    #pragma unroll
    for (int t = 0; t < T_; ++t) {
        uint_t outp[4];
        #pragma unroll
        for (int i2 = 0; i2 < 4; ++i2) {
            float o0 = fmaf(w0, p[2*i2],   fmaf(w1, c[2*i2],   w2 * n[2*i2]));
            float o1 = fmaf(w0, p[2*i2+1], fmaf(w1, c[2*i2+1], w2 * n[2*i2+1]));
            ushort_t u0 = f2bf(o0), u1 = f2bf(o1);
            float r0 = bf2f(u0), r1 = bf2f(u1);
            s += r0 + r1; ss = fmaf(r0, r0, fmaf(r1, r1, ss));
            outp[i2] = (uint_t)u0 | ((uint_t)u1 << 16);
        }
        uint4 r; r.x = outp[0]; r.y = outp[1]; r.z = outp[2]; r.w = outp[3];
        keep[t] = r;
        *(uint4*)(op + t*HW_) = r;

        #pragma unroll
        for (int i = 0; i < 8; ++i) { p[i] = c[i]; c[i] = n[i]; }
        if (t + 2 < T_) {
            loadnorm8(sp + (t+2)*HW_, a, bb, n);
        } else {
            #pragma unroll
            for (int i = 0; i < 8; ++i) n[i] = 0.f;
        }
    }

    // stats3 over the whole channel (block-exact, 8 waves)
    #pragma unroll
    for (int m = 32; m > 0; m >>= 1) {
        s  += __shfl_xor(s,  m);
        ss += __shfl_xor(ss, m);
    }
    __shared__ float ls[8], lss[8];
    __shared__ float sa, sb;
    int wid = tid >> 6, lane = tid & 63;
    if (lane == 0) { ls[wid] = s; lss[wid] = ss; }
    __syncthreads();
    if (tid == 0) {
        float st = 0.f, sst = 0.f;
        #pragma unroll
        for (int i = 0; i < 8; ++i) { st += ls[i]; sst += lss[i]; }
        float m = st * (1.f/THW);
        float v = sst * (1.f/THW) - m*m;
        float is = 1.f / sqrtf(v + EPS);
        g_stats[SM3  + bc] = m;
        g_stats[SIS3 + bc] = is;
        sa = is; sb = -m * is;
    }
    __syncthreads();

    // SE relu-mean from register-kept outputs (no HBM re-read)
    const float a3 = sa, b3 = sb;
    float s2 = 0.f;
    #pragma unroll
    for (int t = 0; t < T_; ++t) {
        uint_t uu[4] = {keep[t].x, keep[t].y, keep[t].z, keep[t].w};
        #pragma unroll
        for (int j = 0; j < 4; ++j) {
            s2 += fmaxf(fmaf(__uint_as_float(uu[j] << 16),         a3, b3), 0.f);
            s2 += fmaxf(fmaf(__uint_as_float(uu[j] & 0xffff0000u), a3, b3), 0.f);
        }
    }
    #pragma unroll
    for (int m = 32; m > 0; m >>= 1) s2 += __shfl_xor(s2, m);
    if (lane == 0) ls[wid] = s2;
    __syncthreads();
    if (tid == 0) {
        float st = 0.f;
        #pragma unroll
        for (int i = 0; i < 8; ++i) st += ls[i];
        g_stats[SSES + bc] = st * (1.f/THW);
    }
}

// ------------ SE MLP -> fold sigmoid scale into proj's alpha/beta -------------
__global__ __launch_bounds__(256) void k_semlp(const float* __restrict__ wse1,
                                               const float* __restrict__ wse2) {
    __shared__ float mv[HID];
    __shared__ float y1[64];
    const int bb = blockIdx.x, tid = threadIdx.x;
    mv[tid] = g_stats[SSES + bb*HID + tid];
    __syncthreads();
    if (tid < 64) {
        float acc = 0.f;
        #pragma unroll 8
        for (int c = 0; c < HID; ++c) acc = fmaf(wse1[tid*HID + c], mv[c], acc);
        y1[tid] = fmaxf(acc, 0.f);
    }
    __syncthreads();
    float z = 0.f;
    #pragma unroll
    for (int c = 0; c < 64; ++c) z = fmaf(wse2[tid*64 + c], y1[c], z);
    float se = 1.f / (1.f + expf(-z));
    const int bc = bb*HID + tid;
    float al = g_stats[SIS3 + bc] * se;
    g_stats[SAL + bc] = al;
    g_stats[SBE + bc] = -g_stats[SM3 + bc] * al;
}

// ------------ final fused: proj stats + norm + shortcut + maxpool -------------
__global__ __launch_bounds__(1024) void k_final(const float* __restrict__ proj,
                                                const float* __restrict__ x,
                                                float* __restrict__ out, int b0) {
    const int bo  = blockIdx.x;
    const int tid = threadIdx.x;
    const float* p = proj + (size_t)bo * THW;

    float s = 0.f, ss = 0.f;
    #pragma unroll
    for (int i = 0; i < THW/(1024*4); ++i) {
        float4 u = *(const float4*)(p + i*4096 + tid*4);
        s += u.x; ss = fmaf(u.x, u.x, ss);
        s += u.y; ss = fmaf(u.y, u.y, ss);
        s += u.z; ss = fmaf(u.z, u.z, ss);
        s += u.w; ss = fmaf(u.w, u.w, ss);
    }
    #pragma unroll
    for (int off = 32; off > 0; off >>= 1) {
        s  += __shfl_down(s,  off, 64);
        ss += __shfl_down(ss, off, 64);
    }
    __shared__ float ls[16], lss[16];
    __shared__ float sa, sb;
    int wid = tid >> 6, lane = tid & 63;
    if (lane == 0) { ls[wid] = s; lss[wid] = ss; }
    __syncthreads();
    if (tid == 0) {
        float st = 0.f, sst = 0.f;
        #pragma unroll
        for (int i = 0; i < 16; ++i) { st += ls[i]; sst += lss[i]; }
        float m = st * (1.f/THW);
        float v = sst * (1.f/THW) - m*m;
        float is = 1.f / sqrtf(v + EPS);
        sa = is; sb = -m * is;
    }
    __syncthreads();
    const float a = sa, bb = sb;

    const size_t gbase = (size_t)(b0*COUT + bo) * THW;
    float* op = out + (size_t)(b0*COUT + bo) * (T_*1024);
    #pragma unroll
    for (int i = 0; i < 16; ++i) {
        int idx = i*1024 + tid;
        int xx = idx & 31, yy = (idx >> 5) & 31, t = idx >> 10;
        float m = -3.4e38f;
        #pragma unroll
        for (int r = 0; r < 2; ++r) {
            size_t off = (size_t)t*HW_ + (size_t)(2*yy + r)*W_ + 2*xx;
            float2 p2 = *(const float2*)(p + off);
            float2 x2 = *(const float2*)(x + gbase + off);
            float v0 = fmaf(p2.x, a, bb) + x2.x;
            float v1 = fmaf(p2.y, a, bb) + x2.y;
            m = fmaxf(m, fmaxf(v0, v1));
        }
        op[idx] = m;
    }
}

extern "C" void kernel_launch(void* const* d_in, const int* in_sizes, int n_in,
                              void* d_out, int out_size, void* d_ws, size_t ws_size,
                              hipStream_t stream) {
    const float* x     = (const float*)d_in[0];
    const float* w1    = (const float*)d_in[1];
    const float* wdws  = (const float*)d_in[2];
    const float* wdwt  = (const float*)d_in[3];
    const float* wse1  = (const float*)d_in[4];
    const float* wse2  = (const float*)d_in[5];
    const float* wproj = (const float*)d_in[6];
    float* out = (float*)d_out;

    const size_t perb = 2ull * HID * THW * sizeof(ushort_t);   // 64 MB
    int nb = (ws_size >= 4*perb) ? 4 : (ws_size >= 2*perb) ? 2 : 1;

    k_prep<<<64, 256, 0, stream>>>(w1, wproj);

    for (int b0 = 0; b0 < B_; b0 += nb) {
        char* ws = (char*)d_ws;
        ushort_t* h1   = (ushort_t*)ws;
        ushort_t* h2   = (ushort_t*)(ws + (size_t)nb * HID*THW*2);
        ushort_t* h3   = h1;
        float*    proj = (float*)h2;

        k_expand    <<<dim3(THW/64, nb), 256, 0, stream>>>(x, h1, b0);
        k_stats_bf16<<<nb*HID, 256, 0, stream>>>(h1, SM1, SIS1);
        k_dws       <<<nb*HID, 256, 0, stream>>>(h1, wdws, h2);
        k_dwt       <<<nb*HID, 512, 0, stream>>>(h2, wdwt, h3);
        k_semlp     <<<nb, 256, 0, stream>>>(wse1, wse2);
        k_proj      <<<dim3(THW/128, nb), 256, 0, stream>>>(h3, proj);
        k_final     <<<nb*COUT, 1024, 0, stream>>>(proj, x, out, b0);
    }
}

// Round 10
// 362.543 us; speedup vs baseline: 4.3291x; 1.1551x over previous
//
#include <hip/hip_runtime.h>
#include <hip/hip_bf16.h>

#define B_   4
#define CIN  64
#define HID  256
#define COUT 64
#define T_   16
#define H_   64
#define W_   64
#define HW_  (H_*W_)       // 4096
#define THW  (T_*HW_)      // 65536
#define EPS  1e-5f

typedef unsigned short ushort_t;
typedef unsigned int   uint_t;
typedef short bf16x8 __attribute__((ext_vector_type(8)));
typedef float f32x4  __attribute__((ext_vector_type(4)));

// ---- stats in static device memory -------------------------------------------
#define SM1   0
#define SIS1  1024
#define SM2   2048
#define SIS2  3072
#define SM3   4096
#define SIS3  5120
#define SSES  6144
#define SAL   7168
#define SBE   8192
__device__ float g_stats[10240];
__device__ float g_p2s[16384], g_p2ss[16384];   // per (bc,t) dws output partials
// packed bf16 weights in MFMA fragment order: [0:16384) expand, [16384:32768) proj
__device__ ushort_t g_wpack[32768];

__device__ __forceinline__ float bf2f(ushort_t u) {
    return __uint_as_float(((uint_t)u) << 16);
}
__device__ __forceinline__ ushort_t f2bf(float f) {
    uint_t u = __float_as_uint(f);
    uint_t r = u + 0x7fffu + ((u >> 16) & 1u);   // round-to-nearest-even
    return (ushort_t)(r >> 16);
}
__device__ __forceinline__ void loadnorm8(const ushort_t* p, float a, float bb,
                                          float* v) {
    uint4 u = *(const uint4*)p;
    uint_t uu[4] = {u.x, u.y, u.z, u.w};
    #pragma unroll
    for (int j = 0; j < 4; ++j) {
        v[2*j]   = fmaxf(fmaf(__uint_as_float(uu[j] << 16),         a, bb), 0.f);
        v[2*j+1] = fmaxf(fmaf(__uint_as_float(uu[j] & 0xffff0000u), a, bb), 0.f);
    }
}

// ---- pack w1 + wproj into bf16 fragment order --------------------------------
__global__ __launch_bounds__(256) void k_prep(const float* __restrict__ w1,
                                              const float* __restrict__ wproj) {
    int idx = blockIdx.x*256 + threadIdx.x;        // 0..16383
    {
        int j = idx & 7, lane = (idx>>3) & 63, ot = (idx>>9) & 3;
        int ks = (idx>>11) & 1, wv = idx >> 12;
        int ln = lane & 15, q = lane >> 4;
        int o = wv*64 + ot*16 + ln, k = ks*32 + q*8 + j;
        g_wpack[idx] = f2bf(w1[o*CIN + k]);
    }
    {
        int j = idx & 7, lane = (idx>>3) & 63, ot = (idx>>9) & 3, kg = idx >> 11;
        int ln = lane & 15, q = lane >> 4;
        int o = ot*16 + ln, k = kg*32 + q*8 + j;
        g_wpack[16384 + idx] = f2bf(wproj[o*HID + k]);
    }
}

// ============ expand 1x1 via MFMA (A from packed global, float4 B-stage) ======
__global__ __launch_bounds__(256) void k_expand(const float* __restrict__ x,
                                                ushort_t* __restrict__ h1, int b0) {
    __shared__ ushort_t Bs[64*72];       // B[k][n], stride 72, rotated cols
    const int tid = threadIdx.x;
    const int bb  = blockIdx.y, gb = b0 + bb;
    const int pos0 = blockIdx.x * 64;
    const int lane = tid & 63, wv = tid >> 6;
    const int q = lane >> 4, ln = lane & 15;

    bf16x8 af[2][4];
    #pragma unroll
    for (int ks = 0; ks < 2; ++ks)
        #pragma unroll
        for (int ot = 0; ot < 4; ++ot)
            af[ks][ot] = *(const bf16x8*)&g_wpack[(((wv*2+ks)*4+ot)<<9) + lane*8];

    #pragma unroll
    for (int i = 0; i < 4; ++i) {
        int lin = i*1024 + tid*4;
        int k = lin >> 6, n0 = lin & 63;
        float4 v = *(const float4*)&x[(size_t)(gb*CIN + k) * THW + pos0 + n0];
        ushort_t* d = &Bs[k*72 + ((n0 + 16*((k>>3)&3)) & 63)];
        d[0] = f2bf(v.x); d[1] = f2bf(v.y); d[2] = f2bf(v.z); d[3] = f2bf(v.w);
    }
    __syncthreads();

    f32x4 acc[4][4];
    #pragma unroll
    for (int i = 0; i < 4; ++i)
        #pragma unroll
        for (int j = 0; j < 4; ++j)
            acc[i][j] = (f32x4){0.f,0.f,0.f,0.f};

    #pragma unroll
    for (int ks = 0; ks < 2; ++ks) {
        bf16x8 bfr[4];
        #pragma unroll
        for (int nt = 0; nt < 4; ++nt) {
            union { short s[8]; bf16x8 v; } bu;
            #pragma unroll
            for (int j = 0; j < 8; ++j) {
                int k = ks*32 + q*8 + j;
                int nn = (nt*16 + ln + 16*((k>>3)&3)) & 63;
                bu.s[j] = (short)Bs[k*72 + nn];
            }
            bfr[nt] = bu.v;
        }
        #pragma unroll
        for (int ot = 0; ot < 4; ++ot)
            #pragma unroll
            for (int nt = 0; nt < 4; ++nt)
                acc[ot][nt] = __builtin_amdgcn_mfma_f32_16x16x32_bf16(
                    af[ks][ot], bfr[nt], acc[ot][nt], 0, 0, 0);
    }

    #pragma unroll
    for (int ot = 0; ot < 4; ++ot)
        #pragma unroll
        for (int nt = 0; nt < 4; ++nt)
            #pragma unroll
            for (int r = 0; r < 4; ++r) {
                int o = wv*64 + ot*16 + q*4 + r;
                int n = nt*16 + ln;
                h1[((size_t)bb*HID + o)*THW + pos0 + n] = f2bf(acc[ot][nt][r]);
            }
}

// ============ proj 1x1 via MFMA (uint2 B-stage, alpha==0 skip) ================
__global__ __launch_bounds__(256) void k_proj(const ushort_t* __restrict__ h3,
                                              float* __restrict__ proj) {
    __shared__ ushort_t Bs[64*136];      // B[klocal][n], stride 136, rotated cols
    const int tid = threadIdx.x;
    const int bb  = blockIdx.y;
    const int pos0 = blockIdx.x * 128;
    const int lane = tid & 63, wv = tid >> 6;
    const int q = lane >> 4, ln = lane & 15;

    f32x4 acc[4][2];
    #pragma unroll
    for (int i = 0; i < 4; ++i) {
        acc[i][0] = (f32x4){0.f,0.f,0.f,0.f};
        acc[i][1] = (f32x4){0.f,0.f,0.f,0.f};
    }

    for (int kc = 0; kc < 4; ++kc) {
        #pragma unroll
        for (int i = 0; i < 8; ++i) {
            int lin = i*1024 + tid*4;
            int kl = lin >> 7, n0 = lin & 127;
            int ch = bb*HID + kc*64 + kl;
            float al = g_stats[SAL + ch], be = g_stats[SBE + ch];
            ushort_t* d = &Bs[kl*136 + ((n0 + 16*((kl>>3)&7)) & 127)];
            if (al == 0.f) {                 // zero-forced TIM channels
                d[0] = 0; d[1] = 0; d[2] = 0; d[3] = 0;
            } else {
                uint2 u = *(const uint2*)&h3[(size_t)ch * THW + pos0 + n0];
                float f0 = __uint_as_float(u.x << 16);
                float f1 = __uint_as_float(u.x & 0xffff0000u);
                float f2 = __uint_as_float(u.y << 16);
                float f3 = __uint_as_float(u.y & 0xffff0000u);
                d[0] = f2bf(fmaxf(fmaf(f0, al, be), 0.f));
                d[1] = f2bf(fmaxf(fmaf(f1, al, be), 0.f));
                d[2] = f2bf(fmaxf(fmaf(f2, al, be), 0.f));
                d[3] = f2bf(fmaxf(fmaf(f3, al, be), 0.f));
            }
        }
        __syncthreads();

        #pragma unroll
        for (int ks = 0; ks < 2; ++ks) {
            int kg = kc*2 + ks;
            bf16x8 af[4];
            #pragma unroll
            for (int ot = 0; ot < 4; ++ot)
                af[ot] = *(const bf16x8*)&g_wpack[16384 + ((kg*4+ot)<<9) + lane*8];
            bf16x8 bfr[2];
            #pragma unroll
            for (int nt = 0; nt < 2; ++nt) {
                union { short s[8]; bf16x8 v; } bu;
                #pragma unroll
                for (int j = 0; j < 8; ++j) {
                    int kl = ks*32 + q*8 + j;
                    int nn = (wv*32 + nt*16 + ln + 16*((kl>>3)&7)) & 127;
                    bu.s[j] = (short)Bs[kl*136 + nn];
                }
                bfr[nt] = bu.v;
            }
            #pragma unroll
            for (int ot = 0; ot < 4; ++ot)
                #pragma unroll
                for (int nt = 0; nt < 2; ++nt)
                    acc[ot][nt] = __builtin_amdgcn_mfma_f32_16x16x32_bf16(
                        af[ot], bfr[nt], acc[ot][nt], 0, 0, 0);
        }
        __syncthreads();
    }

    #pragma unroll
    for (int ot = 0; ot < 4; ++ot)
        #pragma unroll
        for (int nt = 0; nt < 2; ++nt)
            #pragma unroll
            for (int r = 0; r < 4; ++r) {
                int o = ot*16 + q*4 + r;
                int n = wv*32 + nt*16 + ln;
                proj[((size_t)bb*COUT + o)*THW + pos0 + n] = acc[ot][nt][r];
            }
}

// ---------------- per-(bb,c) mean / inv_sd over THW, bf16 source (h1 only) ----
__global__ __launch_bounds__(256) void k_stats_bf16(const ushort_t* __restrict__ src,
                                                    int moff, int isoff) {
    const int bc = blockIdx.x;
    const int tid = threadIdx.x;
    const ushort_t* p = src + (size_t)bc * THW;
    float s = 0.f, ss = 0.f;
    #pragma unroll 4
    for (int i = 0; i < THW/(256*8); ++i) {       // 32 iters, 16B/lane
        uint4 u = *(const uint4*)(p + i*2048 + tid*8);
        uint_t w[4] = {u.x, u.y, u.z, u.w};
        #pragma unroll
        for (int j = 0; j < 4; ++j) {
            float f0 = __uint_as_float(w[j] << 16);
            float f1 = __uint_as_float(w[j] & 0xffff0000u);
            s += f0; ss = fmaf(f0, f0, ss);
            s += f1; ss = fmaf(f1, f1, ss);
        }
    }
    #pragma unroll
    for (int off = 32; off > 0; off >>= 1) {
        s  += __shfl_down(s,  off, 64);
        ss += __shfl_down(ss, off, 64);
    }
    __shared__ float ls[4], lss[4];
    int wid = tid >> 6, lane = tid & 63;
    if (lane == 0) { ls[wid] = s; lss[wid] = ss; }
    __syncthreads();
    if (tid == 0) {
        float st  = ls[0]+ls[1]+ls[2]+ls[3];
        float sst = lss[0]+lss[1]+lss[2]+lss[3];
        float m = st * (1.f/THW);
        float v = sst * (1.f/THW) - m*m;
        g_stats[moff  + bc] = m;
        g_stats[isoff + bc] = 1.f / sqrtf(v + EPS);
    }
}

// ------------ spatial dw 3x3: one block per (t, channel), plane in LDS --------
__global__ __launch_bounds__(256) void k_dws(const ushort_t* __restrict__ h1,
                                             const float* __restrict__ wdw,
                                             ushort_t* __restrict__ h2) {
    const int tid = threadIdx.x;
    const int t   = blockIdx.x;
    const int bc  = blockIdx.y;
    const int o   = bc & (HID-1);
    const int pidx = bc*16 + t;

    const bool zeroall = (o >= 32 && o < 64);
    const bool zerot   = (o < 32 && t == T_-1);
    if (zeroall || zerot) {                 // raw-zero plane, never written/read
        if (tid == 0) { g_p2s[pidx] = 0.f; g_p2ss[pidx] = 0.f; }
        return;
    }
    const int ts = (o < 32) ? t + 1 : t;
    const float a  = g_stats[SIS1 + bc];
    const float bb = -g_stats[SM1 + bc] * a;
    const ushort_t* sp = h1 + (size_t)bc * THW + ts*HW_;
    ushort_t*       op = h2 + (size_t)bc * THW + t*HW_;

    __shared__ float pl[64*66];             // normalized plane, row stride 66
    #pragma unroll
    for (int j = 0; j < 2; ++j) {
        int lin = j*2048 + tid*8;
        int y = lin >> 6, xx = lin & 63;
        float v[8];
        loadnorm8(sp + lin, a, bb, v);
        float* dst = &pl[y*66 + xx];
        #pragma unroll
        for (int i = 0; i < 8; ++i) dst[i] = v[i];
    }
    __syncthreads();

    float wf[9];
    #pragma unroll
    for (int k = 0; k < 9; ++k) wf[k] = wdw[o*9 + k];

    float s = 0.f, ss = 0.f;
    #pragma unroll
    for (int g = 0; g < 2; ++g) {
        int lin = g*2048 + tid*8;
        int y = lin >> 6, x0 = lin & 63;
        float v[3][10];
        #pragma unroll
        for (int dy = 0; dy < 3; ++dy) {
            int yy = y + dy - 1;
            if (yy < 0 || yy >= H_) {
                #pragma unroll
                for (int j = 0; j < 10; ++j) v[dy][j] = 0.f;
            } else {
                const float* rp = &pl[yy*66];
                v[dy][0] = (x0 == 0)  ? 0.f : rp[x0-1];
                #pragma unroll
                for (int i = 0; i < 8; ++i) v[dy][1+i] = rp[x0+i];
                v[dy][9] = (x0 == 56) ? 0.f : rp[x0+8];
            }
        }
        uint_t outp[4];
        #pragma unroll
        for (int i2 = 0; i2 < 4; ++i2) {
            float o0 = 0.f, o1 = 0.f;
            #pragma unroll
            for (int dy = 0; dy < 3; ++dy)
                #pragma unroll
                for (int dx = 0; dx < 3; ++dx) {
                    float w = wf[dy*3+dx];
                    o0 = fmaf(w, v[dy][2*i2 + dx],     o0);
                    o1 = fmaf(w, v[dy][2*i2 + 1 + dx], o1);
                }
            ushort_t u0 = f2bf(o0), u1 = f2bf(o1);
            float r0 = bf2f(u0), r1 = bf2f(u1);
            s += r0 + r1; ss = fmaf(r0, r0, fmaf(r1, r1, ss));
            outp[i2] = (uint_t)u0 | ((uint_t)u1 << 16);
        }
        uint4 r; r.x = outp[0]; r.y = outp[1]; r.z = outp[2]; r.w = outp[3];
        *(uint4*)(op + lin) = r;
    }

    #pragma unroll
    for (int m = 32; m > 0; m >>= 1) {
        s  += __shfl_xor(s,  m);
        ss += __shfl_xor(ss, m);
    }
    __shared__ float ls[4], lss[4];
    int wid = tid >> 6, lane = tid & 63;
    if (lane == 0) { ls[wid] = s; lss[wid] = ss; }
    __syncthreads();
    if (tid == 0) {
        g_p2s[pidx]  = ls[0]+ls[1]+ls[2]+ls[3];
        g_p2ss[pidx] = lss[0]+lss[1]+lss[2]+lss[3];
    }
}

// ------------ temporal dw 3, ONE BLOCK PER CHANNEL (+stats3 +SE mean) ---------
__global__ __launch_bounds__(512) void k_dwt(const ushort_t* __restrict__ h2,
                                             const float* __restrict__ wdt,
                                             ushort_t* __restrict__ h3) {
    const int tid = threadIdx.x;                  // 0..511
    const int bc  = blockIdx.x;
    const int o   = bc & (HID-1);
    __shared__ float ls[8], lss[8];
    __shared__ float sa, sb;
    int wid = tid >> 6, lane = tid & 63;

    if (o >= 32 && o < 64) {                      // zero channel: stats only
        if (tid == 0) {
            g_stats[SM3  + bc] = 0.f;
            g_stats[SIS3 + bc] = 1.f / sqrtf(EPS);
            g_stats[SSES + bc] = 0.f;
        }
        return;
    }

    // m2/is2 from k_dws partials (16 planes)
    {
        float ps  = (tid < 16) ? g_p2s [bc*16 + tid] : 0.f;
        float pss = (tid < 16) ? g_p2ss[bc*16 + tid] : 0.f;
        #pragma unroll
        for (int m = 8; m > 0; m >>= 1) {
            ps  += __shfl_xor(ps,  m);
            pss += __shfl_xor(pss, m);
        }
        if (tid == 0) {
            float m = ps * (1.f/THW);
            float v = pss * (1.f/THW) - m*m;
            float is = 1.f / sqrtf(v + EPS);
            g_stats[SM2  + bc] = m;
            g_stats[SIS2 + bc] = is;
            sa = is; sb = -m * is;
        }
    }
    __syncthreads();
    const float a = sa, bb = sb;
    const bool last_invalid = (o < 32);           // h2 plane 15 is raw-zero, unwritten
    const float znorm = fmaxf(bb, 0.f);           // relu(norm(raw 0)) — THE FIX
    const float w0 = wdt[o*3+0], w1 = wdt[o*3+1], w2 = wdt[o*3+2];
    const int pos = tid * 8;
    const ushort_t* sp = h2 + (size_t)bc * THW + pos;
    ushort_t*       op = h3 + (size_t)bc * THW + pos;

    float p[8], c[8], n[8];
    #pragma unroll
    for (int i = 0; i < 8; ++i) p[i] = 0.f;
    loadnorm8(sp,       a, bb, c);
    loadnorm8(sp + HW_, a, bb, n);

    uint4 keep[16];
    float s = 0.f, ss = 0.f;
    #pragma unroll
    for (int t = 0; t < T_; ++t) {
        uint_t outp[4];
        #pragma unroll
        for (int i2 = 0; i2 < 4; ++i2) {
            float o0 = fmaf(w0, p[2*i2],   fmaf(w1, c[2*i2],   w2 * n[2*i2]));
            float o1 = fmaf(w0, p[2*i2+1], fmaf(w1, c[2*i2+1], w2 * n[2*i2+1]));
            ushort_t u0 = f2bf(o0), u1 = f2bf(o1);
            float r0 = bf2f(u0), r1 = bf2f(u1);
            s += r0 + r1; ss = fmaf(r0, r0, fmaf(r1, r1, ss));
            outp[i2] = (uint_t)u0 | ((uint_t)u1 << 16);
        }
        uint4 r; r.x = outp[0]; r.y = outp[1]; r.z = outp[2]; r.w = outp[3];
        keep[t] = r;
        *(uint4*)(op + t*HW_) = r;

        #pragma unroll
        for (int i = 0; i < 8; ++i) { p[i] = c[i]; c[i] = n[i]; }
        if (t + 2 < T_) {
            if (last_invalid && t + 2 == T_-1) {
                #pragma unroll
                for (int i = 0; i < 8; ++i) n[i] = znorm;   // normalized raw-zero plane
            } else {
                loadnorm8(sp + (t+2)*HW_, a, bb, n);
            }
        } else {
            #pragma unroll
            for (int i = 0; i < 8; ++i) n[i] = 0.f;         // true conv zero-padding
        }
    }

    #pragma unroll
    for (int m = 32; m > 0; m >>= 1) {
        s  += __shfl_xor(s,  m);
        ss += __shfl_xor(ss, m);
    }
    if (lane == 0) { ls[wid] = s; lss[wid] = ss; }
    __syncthreads();
    if (tid == 0) {
        float st = 0.f, sst = 0.f;
        #pragma unroll
        for (int i = 0; i < 8; ++i) { st += ls[i]; sst += lss[i]; }
        float m = st * (1.f/THW);
        float v = sst * (1.f/THW) - m*m;
        float is = 1.f / sqrtf(v + EPS);
        g_stats[SM3  + bc] = m;
        g_stats[SIS3 + bc] = is;
        sa = is; sb = -m * is;
    }
    __syncthreads();

    const float a3 = sa, b3 = sb;
    float s2 = 0.f;
    #pragma unroll
    for (int t = 0; t < T_; ++t) {
        uint_t uu[4] = {keep[t].x, keep[t].y, keep[t].z, keep[t].w};
        #pragma unroll
        for (int j = 0; j < 4; ++j) {
            s2 += fmaxf(fmaf(__uint_as_float(uu[j] << 16),         a3, b3), 0.f);
            s2 += fmaxf(fmaf(__uint_as_float(uu[j] & 0xffff0000u), a3, b3), 0.f);
        }
    }
    #pragma unroll
    for (int m = 32; m > 0; m >>= 1) s2 += __shfl_xor(s2, m);
    if (lane == 0) ls[wid] = s2;
    __syncthreads();
    if (tid == 0) {
        float st = 0.f;
        #pragma unroll
        for (int i = 0; i < 8; ++i) st += ls[i];
        g_stats[SSES + bc] = st * (1.f/THW);
    }
}

// ------------ SE MLP -> fold sigmoid scale into proj's alpha/beta -------------
__global__ __launch_bounds__(256) void k_semlp(const float* __restrict__ wse1,
                                               const float* __restrict__ wse2) {
    __shared__ float mv[HID];
    __shared__ float y1[64];
    const int bb = blockIdx.x, tid = threadIdx.x;
    mv[tid] = g_stats[SSES + bb*HID + tid];
    __syncthreads();
    if (tid < 64) {
        float acc = 0.f;
        #pragma unroll 8
        for (int c = 0; c < HID; ++c) acc = fmaf(wse1[tid*HID + c], mv[c], acc);
        y1[tid] = fmaxf(acc, 0.f);
    }
    __syncthreads();
    float z = 0.f;
    #pragma unroll
    for (int c = 0; c < 64; ++c) z = fmaf(wse2[tid*64 + c], y1[c], z);
    float se = 1.f / (1.f + expf(-z));
    const int bc = bb*HID + tid;
    float al = g_stats[SIS3 + bc] * se;
    if (tid >= 32 && tid < 64) al = 0.f;   // zero-TIM channels: exact zero contribution
    g_stats[SAL + bc] = al;
    g_stats[SBE + bc] = -g_stats[SM3 + bc] * al;
}

// ------------ final fused: proj stats + norm + shortcut + maxpool -------------
__global__ __launch_bounds__(1024) void k_final(const float* __restrict__ proj,
                                                const float* __restrict__ x,
                                                float* __restrict__ out, int b0) {
    const int bo  = blockIdx.x;
    const int tid = threadIdx.x;
    const float* p = proj + (size_t)bo * THW;

    float s = 0.f, ss = 0.f;
    #pragma unroll
    for (int i = 0; i < THW/(1024*4); ++i) {
        float4 u = *(const float4*)(p + i*4096 + tid*4);
        s += u.x; ss = fmaf(u.x, u.x, ss);
        s += u.y; ss = fmaf(u.y, u.y, ss);
        s += u.z; ss = fmaf(u.z, u.z, ss);
        s += u.w; ss = fmaf(u.w, u.w, ss);
    }
    #pragma unroll
    for (int off = 32; off > 0; off >>= 1) {
        s  += __shfl_down(s,  off, 64);
        ss += __shfl_down(ss, off, 64);
    }
    __shared__ float ls[16], lss[16];
    __shared__ float sa, sb;
    int wid = tid >> 6, lane = tid & 63;
    if (lane == 0) { ls[wid] = s; lss[wid] = ss; }
    __syncthreads();
    if (tid == 0) {
        float st = 0.f, sst = 0.f;
        #pragma unroll
        for (int i = 0; i < 16; ++i) { st += ls[i]; sst += lss[i]; }
        float m = st * (1.f/THW);
        float v = sst * (1.f/THW) - m*m;
        float is = 1.f / sqrtf(v + EPS);
        sa = is; sb = -m * is;
    }
    __syncthreads();
    const float a = sa, bb = sb;

    const size_t gbase = (size_t)(b0*COUT + bo) * THW;
    float* op = out + (size_t)(b0*COUT + bo) * (T_*1024);
    #pragma unroll
    for (int i = 0; i < 16; ++i) {
        int idx = i*1024 + tid;
        int xx = idx & 31, yy = (idx >> 5) & 31, t = idx >> 10;
        float m = -3.4e38f;
        #pragma unroll
        for (int r = 0; r < 2; ++r) {
            size_t off = (size_t)t*HW_ + (size_t)(2*yy + r)*W_ + 2*xx;
            float2 p2 = *(const float2*)(p + off);
            float2 x2 = *(const float2*)(x + gbase + off);
            float v0 = fmaf(p2.x, a, bb) + x2.x;
            float v1 = fmaf(p2.y, a, bb) + x2.y;
            m = fmaxf(m, fmaxf(v0, v1));
        }
        op[idx] = m;
    }
}

extern "C" void kernel_launch(void* const* d_in, const int* in_sizes, int n_in,
                              void* d_out, int out_size, void* d_ws, size_t ws_size,
                              hipStream_t stream) {
    const float* x     = (const float*)d_in[0];
    const float* w1    = (const float*)d_in[1];
    const float* wdws  = (const float*)d_in[2];
    const float* wdwt  = (const float*)d_in[3];
    const float* wse1  = (const float*)d_in[4];
    const float* wse2  = (const float*)d_in[5];
    const float* wproj = (const float*)d_in[6];
    float* out = (float*)d_out;

    const size_t perb = 2ull * HID * THW * sizeof(ushort_t);   // 64 MB
    int nb = (ws_size >= 4*perb) ? 4 : (ws_size >= 2*perb) ? 2 : 1;

    k_prep<<<64, 256, 0, stream>>>(w1, wproj);

    for (int b0 = 0; b0 < B_; b0 += nb) {
        char* ws = (char*)d_ws;
        ushort_t* h1   = (ushort_t*)ws;
        ushort_t* h2   = (ushort_t*)(ws + (size_t)nb * HID*THW*2);
        ushort_t* h3   = h1;
        float*    proj = (float*)h2;

        k_expand    <<<dim3(THW/64, nb), 256, 0, stream>>>(x, h1, b0);
        k_stats_bf16<<<nb*HID, 256, 0, stream>>>(h1, SM1, SIS1);
        k_dws       <<<dim3(T_, nb*HID), 256, 0, stream>>>(h1, wdws, h2);
        k_dwt       <<<nb*HID, 512, 0, stream>>>(h2, wdwt, h3);
        k_semlp     <<<nb, 256, 0, stream>>>(wse1, wse2);
        k_proj      <<<dim3(THW/128, nb), 256, 0, stream>>>(h3, proj);
        k_final     <<<nb*COUT, 1024, 0, stream>>>(proj, x, out, b0);
    }
}